// Round 8
// baseline (97.374 us; speedup 1.0000x reference)
//
#include <hip/hip_runtime.h>
#include <hip/hip_bf16.h>
#include <math.h>

#define NN 4096
#define DD 128

typedef __attribute__((ext_vector_type(8))) short bf16x8;
typedef __attribute__((ext_vector_type(4))) float f32x4;
#define AS3 __attribute__((address_space(3)))

// ws layout (doubles): gemm-loss slots ws[k*8], k=0..15; ws[128]=bqc1,
// ws[129]=bqc2, ws[130]=fdc.

__device__ __forceinline__ void gload_lds16(const float* g, float* l) {
    __builtin_amdgcn_global_load_lds((const __attribute__((address_space(1))) char*)g,
                                     (AS3 char*)l, 16, 0, 0);
}

// ---- fused prep: convert F (f32 [d][i]) -> bf16 [i][d]  +  bqc partials ----
__global__ __launch_bounds__(256)
void convert_bqc_kernel(const float* __restrict__ FP, const float* __restrict__ FM,
                        const float* __restrict__ B,
                        __hip_bfloat16* __restrict__ FPt, __hip_bfloat16* __restrict__ FMt,
                        double* __restrict__ ws)
{
    const int y = blockIdx.y;
    const float* src = y ? FM : FP;
    __hip_bfloat16* dst = y ? FMt : FPt;
    const int t  = threadIdx.x;
    const int il = t & 127;
    const int dh = t >> 7;
    const int i  = blockIdx.x * 128 + il;
    float s = 0.f;
    #pragma unroll
    for (int it = 0; it < 8; ++it) {
        const int d0 = dh * 64 + it * 8;
        float a[8];
        #pragma unroll
        for (int j = 0; j < 8; ++j) {
            a[j] = src[(long)(d0 + j) * NN + i];
            const float b = B[(long)(d0 + j) * NN + i];
            const float d = a[j] - b;
            s += d * d;
        }
        union { __hip_bfloat162 h[4]; bf16x8 v; } p;
        #pragma unroll
        for (int j = 0; j < 4; ++j)
            p.h[j] = __float22bfloat162_rn(make_float2(a[2*j], a[2*j+1]));
        *(bf16x8*)&dst[(long)i * DD + d0] = p.v;
    }
    __shared__ float red[4];
    #pragma unroll
    for (int off = 32; off; off >>= 1) s += __shfl_down(s, off);
    if ((t & 63) == 0) red[t >> 6] = s;
    __syncthreads();
    if (t == 0)
        atomicAdd(&ws[128 + y], (double)(red[0] + red[1] + red[2] + red[3]));
}

// ---- fused gemm-loss ------------------------------------------------------
// 512 blocks x 4 waves = 2048 waves; wave-tile 32i x 32j; 24 tiles/wave.
// jt fixed per wave -> both B-side frag sets hoisted. S: 4 LDS buffers,
// stage t+3 each iter via global_load_lds; manual vmcnt(16) keeps
// {S(t+3), af(t+1), S(t+2)} in flight. Epilogue reads S via INLINE-ASM
// ds_read_b32 (compiler-blind: no auto vmcnt(0) drain) + lgkmcnt(0) +
// sched_barrier (rule: compiler hoists reg-only ops past asm waits).
__global__ __launch_bounds__(256, 2)
void gemm_loss_fused(const float* __restrict__ SU, const float* __restrict__ SP,
                     const float* __restrict__ SM,
                     const __hip_bfloat16* __restrict__ FPt_,
                     const __hip_bfloat16* __restrict__ FMt_,
                     double* __restrict__ accum)
{
    __shared__ float sS[4][4][1024];   // [wave][buf][32*32]
    const int t0   = threadIdx.x;
    const int lane = t0 & 63, wid = t0 >> 6;
    const int l15  = lane & 15, l4 = lane >> 4;
    const int w    = blockIdx.x * 4 + wid;              // 0..2047
    const int jt   = w & 127, rr = w >> 7;
    const int j0   = jt * 32;
    const short* FPt = (const short*)FPt_;
    const short* FMt = (const short*)FMt_;

    // hoisted B-side fragments for both F matrices (loaded ONCE)
    bf16x8 bgP[2][4], bgM[2][4];
    #pragma unroll
    for (int n = 0; n < 2; ++n)
        #pragma unroll
        for (int kb = 0; kb < 4; ++kb) {
            const long off = (long)(j0 + n * 16 + l15) * DD + kb * 32 + l4 * 8;
            bgP[n][kb] = *(const bf16x8*)&FPt[off];
            bgM[n][kb] = *(const bf16x8*)&FMt[off];
        }

    // per-lane LDS base byte-offset for the epilogue ds_reads
    const unsigned sbase =
        (unsigned)(unsigned long long)(AS3 float*)&sS[wid][0][l4 * 128 + l15];

    float lsum = 0.f;
    bf16x8 afA[2][4], afB[2][4];

#define TILE_Z(tt)   ((tt) >> 3)
#define TILE_I0(tt)  ((rr + (((tt) & 7) << 4)) << 5)

#define ISSUE_AF(tt, dstbuf)                                                   \
    {                                                                          \
        const int z_  = TILE_Z(tt);                                            \
        const int i0_ = TILE_I0(tt);                                           \
        const short* Fa_ = (z_ == 2) ? FMt : FPt;                              \
        _Pragma("unroll")                                                      \
        for (int m = 0; m < 2; ++m)                                            \
            _Pragma("unroll")                                                  \
            for (int kb = 0; kb < 4; ++kb)                                     \
                dstbuf[m][kb] = *(const bf16x8*)&Fa_[(long)(i0_ + m * 16 + l15) * DD + kb * 32 + l4 * 8]; \
    }

// stage tile srcT's S into LDS buffer dbuf (4 x global_load_lds of 1KB)
#define ISSUE_STAGE(srcT, dbuf)                                                \
    {                                                                          \
        const int z_  = TILE_Z(srcT);                                          \
        const int i0_ = TILE_I0(srcT);                                         \
        const float* S_ = (z_ == 0) ? SU : (z_ == 1) ? SP : SM;                \
        const float* src_ = S_ + (long)(i0_ + (lane >> 3)) * NN + j0 + (lane & 7) * 4; \
        float* d_ = &sS[wid][dbuf][0];                                         \
        _Pragma("unroll")                                                      \
        for (int q_ = 0; q_ < 4; ++q_)                                         \
            gload_lds16(src_ + (long)q_ * 8 * NN, d_ + q_ * 256);              \
    }

#define DSR(dst, OFF) asm volatile("ds_read_b32 %0, %1 offset:" #OFF \
                                   : "=v"(dst) : "v"(lpb))

#define TILE_BODY(tt, cur, nxt)                                                \
    {                                                                          \
        const int tc = (tt);                                                   \
        ISSUE_AF((tc < 23) ? tc + 1 : 23, nxt);                                \
        __builtin_amdgcn_sched_barrier(0);                                     \
        ISSUE_STAGE((tc + 3 < 24) ? tc + 3 : 23, (tc + 3) & 3);                \
        __builtin_amdgcn_sched_barrier(0);                                     \
        asm volatile("s_waitcnt vmcnt(16)");                                   \
        __builtin_amdgcn_sched_barrier(0);                                     \
        const int z_ = TILE_Z(tc);                                             \
        f32x4 acc[2][2] = {};                                                  \
        if (z_ == 1) {                                                         \
            _Pragma("unroll")                                                  \
            for (int kb = 0; kb < 4; ++kb)                                     \
                _Pragma("unroll")                                              \
                for (int m = 0; m < 2; ++m)                                    \
                    _Pragma("unroll")                                          \
                    for (int n = 0; n < 2; ++n)                                \
                        acc[m][n] = __builtin_amdgcn_mfma_f32_16x16x32_bf16(cur[m][kb], bgP[n][kb], acc[m][n], 0, 0, 0); \
        } else {                                                               \
            _Pragma("unroll")                                                  \
            for (int kb = 0; kb < 4; ++kb)                                     \
                _Pragma("unroll")                                              \
                for (int m = 0; m < 2; ++m)                                    \
                    _Pragma("unroll")                                          \
                    for (int n = 0; n < 2; ++n)                                \
                        acc[m][n] = __builtin_amdgcn_mfma_f32_16x16x32_bf16(cur[m][kb], bgM[n][kb], acc[m][n], 0, 0, 0); \
        }                                                                      \
        __builtin_amdgcn_sched_barrier(0);                                     \
        const unsigned lpb = sbase + (unsigned)((tc & 3) * 4096);              \
        float sv[2][2][4];                                                     \
        DSR(sv[0][0][0], 0);    DSR(sv[0][0][1], 128);                         \
        DSR(sv[0][0][2], 256);  DSR(sv[0][0][3], 384);                         \
        DSR(sv[0][1][0], 64);   DSR(sv[0][1][1], 192);                         \
        DSR(sv[0][1][2], 320);  DSR(sv[0][1][3], 448);                         \
        DSR(sv[1][0][0], 2048); DSR(sv[1][0][1], 2176);                        \
        DSR(sv[1][0][2], 2304); DSR(sv[1][0][3], 2432);                        \
        DSR(sv[1][1][0], 2112); DSR(sv[1][1][1], 2240);                        \
        DSR(sv[1][1][2], 2368); DSR(sv[1][1][3], 2496);                        \
        asm volatile("s_waitcnt lgkmcnt(0)");                                  \
        __builtin_amdgcn_sched_barrier(0);                                     \
        const float onep = (z_ == 0) ? 1.0f : 1.0f + 1e-8f;                    \
        _Pragma("unroll")                                                      \
        for (int m = 0; m < 2; ++m)                                            \
            _Pragma("unroll")                                                  \
            for (int n = 0; n < 2; ++n)                                        \
                _Pragma("unroll")                                              \
                for (int r = 0; r < 4; ++r) {                                  \
                    const float o = 0.5f * acc[m][n][r];                       \
                    lsum += fmaf(-sv[m][n][r], o, __logf(o + onep));           \
                }                                                              \
    }

    // prologue: S(0),S(1),af(0),S(2)  (FIFO order chosen so vmcnt(16) works at t=0)
    ISSUE_STAGE(0, 0);
    ISSUE_STAGE(1, 1);
    ISSUE_AF(0, afA);
    ISSUE_STAGE(2, 2);

    #pragma unroll 1
    for (int t = 0; t < 24; t += 2) {
        TILE_BODY(t,     afA, afB);
        TILE_BODY(t + 1, afB, afA);
    }
#undef TILE_BODY
#undef DSR
#undef ISSUE_STAGE
#undef ISSUE_AF
#undef TILE_Z
#undef TILE_I0

    float v = lsum;
    #pragma unroll
    for (int off = 32; off; off >>= 1) v += __shfl_down(v, off);
    if (lane == 0)
        atomicAdd(accum + ((w & 15) << 3), (double)v);
}

// ---------------- fallback path (round-2 kernel, used if ws too small) ------
__global__ __launch_bounds__(256, 2)
void gemm_loss_mfma(const float* __restrict__ S, const float* __restrict__ F1,
                    const float* __restrict__ F2, float eps, double* __restrict__ accum)
{
    __shared__ char lds[2][128 * 256];
    __shared__ float red[4];
    const int t  = threadIdx.x;
    const int i0 = blockIdx.y * 128;
    const int j0 = blockIdx.x * 128;
    {
        const int il   = t & 127;
        const int half = t >> 7;
        const float* c1 = F1 + i0 + il;
        const float* c2 = F2 + j0 + il;
        char* r1 = lds[0] + il * 256;
        char* r2 = lds[1] + il * 256;
        #pragma unroll
        for (int it = 0; it < 8; ++it) {
            const int q  = half * 8 + it;
            const int d0 = q * 8;
            float a[8], b[8];
            #pragma unroll
            for (int j = 0; j < 8; ++j) {
                a[j] = c1[(long)(d0 + j) * NN];
                b[j] = c2[(long)(d0 + j) * NN];
            }
            union { __hip_bfloat162 h[4]; bf16x8 v; } pa, pb;
            #pragma unroll
            for (int j = 0; j < 4; ++j) {
                pa.h[j] = __float22bfloat162_rn(make_float2(a[2*j], a[2*j+1]));
                pb.h[j] = __float22bfloat162_rn(make_float2(b[2*j], b[2*j+1]));
            }
            const int off = (q ^ (il & 15)) << 4;
            *(bf16x8*)(r1 + off) = pa.v;
            *(bf16x8*)(r2 + off) = pb.v;
        }
    }
    __syncthreads();
    const int lane = t & 63;
    const int wid  = t >> 6;
    const int wr   = wid >> 1, wc = wid & 1;
    const int l15  = lane & 15, l4 = lane >> 4;
    float sreg[4][4][4];
    #pragma unroll
    for (int am = 0; am < 4; ++am)
        #pragma unroll
        for (int r = 0; r < 4; ++r) {
            const long gi    = (long)(i0 + wr * 64 + am * 16 + l4 * 4 + r);
            const long basep = gi * NN + j0 + wc * 64 + l15;
            #pragma unroll
            for (int bn = 0; bn < 4; ++bn)
                sreg[am][bn][r] = S[basep + bn * 16];
        }
    f32x4 acc[4][4] = {};
    #pragma unroll
    for (int kb = 0; kb < 4; ++kb) {
        bf16x8 af[4], bgr[4];
        #pragma unroll
        for (int m = 0; m < 4; ++m) {
            const int ia = wr * 64 + m * 16 + l15;
            af[m] = *(const bf16x8*)(lds[0] + ia * 256 + (((kb * 4 + l4) ^ l15) << 4));
            const int jbq = wc * 64 + m * 16 + l15;
            bgr[m] = *(const bf16x8*)(lds[1] + jbq * 256 + (((kb * 4 + l4) ^ l15) << 4));
        }
        #pragma unroll
        for (int m = 0; m < 4; ++m)
            #pragma unroll
            for (int n = 0; n < 4; ++n)
                acc[m][n] = __builtin_amdgcn_mfma_f32_16x16x32_bf16(af[m], bgr[n], acc[m][n], 0, 0, 0);
    }
    float lsum = 0.f;
    #pragma unroll
    for (int m = 0; m < 4; ++m)
        #pragma unroll
        for (int n = 0; n < 4; ++n)
            #pragma unroll
            for (int r = 0; r < 4; ++r) {
                const float o = 0.5f * acc[m][n][r];
                lsum += fmaf(-sreg[m][n][r], o, __logf(1.0f + o + eps));
            }
    float v = lsum;
    #pragma unroll
    for (int off = 32; off; off >>= 1) v += __shfl_down(v, off);
    if ((t & 63) == 0) red[t >> 6] = v;
    __syncthreads();
    if (t == 0) {
        const float tot = red[0] + red[1] + red[2] + red[3];
        atomicAdd(accum, (double)tot);   // slot 0
    }
}

// ---------------- small kernels ----------------
__global__ __launch_bounds__(256)
void bqc_kernel(const float* __restrict__ FP, const float* __restrict__ FM,
                const float* __restrict__ B, double* __restrict__ ws)
{
    __shared__ float red1[4], red2[4];
    const int n4 = DD * NN / 4;
    float s1 = 0.f, s2 = 0.f;
    for (int i = blockIdx.x * blockDim.x + threadIdx.x; i < n4;
         i += gridDim.x * blockDim.x) {
        const float4 p = ((const float4*)FP)[i];
        const float4 m = ((const float4*)FM)[i];
        const float4 b = ((const float4*)B)[i];
        float d;
        d = p.x - b.x; s1 += d * d;  d = p.y - b.y; s1 += d * d;
        d = p.z - b.z; s1 += d * d;  d = p.w - b.w; s1 += d * d;
        d = m.x - b.x; s2 += d * d;  d = m.y - b.y; s2 += d * d;
        d = m.z - b.z; s2 += d * d;  d = m.w - b.w; s2 += d * d;
    }
    const int t = threadIdx.x;
    #pragma unroll
    for (int off = 32; off; off >>= 1) {
        s1 += __shfl_down(s1, off);
        s2 += __shfl_down(s2, off);
    }
    if ((t & 63) == 0) { red1[t >> 6] = s1; red2[t >> 6] = s2; }
    __syncthreads();
    if (t == 0) {
        atomicAdd(&ws[128], (double)(red1[0] + red1[1] + red1[2] + red1[3]));
        atomicAdd(&ws[129], (double)(red2[0] + red2[1] + red2[2] + red2[3]));
    }
}

__global__ __launch_bounds__(256)
void fdc_kernel(const float* __restrict__ FP, const float* __restrict__ FM,
                double* __restrict__ ws)
{
    __shared__ float red[4];
    const float* F = (blockIdx.x >= DD) ? FM : FP;
    const int row = blockIdx.x & (DD - 1);
    float s = 0.f;
    const float4* rowp = (const float4*)&F[(long)row * NN];
    for (int i = threadIdx.x; i < NN / 4; i += blockDim.x) {
        const float4 v = rowp[i];
        s += v.x + v.y + v.z + v.w;
    }
    const int t = threadIdx.x;
    #pragma unroll
    for (int off = 32; off; off >>= 1) s += __shfl_down(s, off);
    if ((t & 63) == 0) red[t >> 6] = s;
    __syncthreads();
    if (t == 0) {
        const double rs = (double)(red[0] + red[1] + red[2] + red[3]);
        atomicAdd(&ws[130], rs * rs);
    }
}

__global__ void finalize_kernel(const double* __restrict__ ws, float* __restrict__ out)
{
    if (threadIdx.x == 0 && blockIdx.x == 0) {
        double s = 0.0;
        #pragma unroll
        for (int k = 0; k < 16; ++k) s += ws[k * 8];
        out[0] = (float)(s + ws[130] + sqrt(ws[128]) + sqrt(ws[129]));
    }
}

extern "C" void kernel_launch(void* const* d_in, const int* in_sizes, int n_in,
                              void* d_out, int out_size, void* d_ws, size_t ws_size,
                              hipStream_t stream)
{
    const float* SU = (const float*)d_in[0];
    const float* SP = (const float*)d_in[1];
    const float* SM = (const float*)d_in[2];
    const float* FP = (const float*)d_in[3];
    const float* FM = (const float*)d_in[4];
    const float* B  = (const float*)d_in[5];
    float*  out = (float*)d_out;
    double* ws  = (double*)d_ws;

    hipMemsetAsync(d_ws, 0, 4096, stream);

    const size_t fb   = (size_t)NN * DD * sizeof(__hip_bfloat16);   // 1 MB
    const size_t need = 4096 + 2 * fb;

    if (ws_size >= need) {
        char* base = (char*)d_ws + 4096;
        __hip_bfloat16* FPt = (__hip_bfloat16*)(base);
        __hip_bfloat16* FMt = (__hip_bfloat16*)(base + fb);
        convert_bqc_kernel<<<dim3(NN / 128, 2), 256, 0, stream>>>(FP, FM, B, FPt, FMt, ws);
        gemm_loss_fused<<<512, 256, 0, stream>>>(SU, SP, SM, FPt, FMt, ws);
        fdc_kernel<<<256, 256, 0, stream>>>(FP, FM, ws);
    } else {
        dim3 grid(NN / 128, NN / 128);
        gemm_loss_mfma<<<grid, 256, 0, stream>>>(SU, FP, FM, 0.0f, ws);
        gemm_loss_mfma<<<grid, 256, 0, stream>>>(SP, FP, FP, 1e-8f, ws);
        gemm_loss_mfma<<<grid, 256, 0, stream>>>(SM, FM, FM, 1e-8f, ws);
        bqc_kernel<<<512, 256, 0, stream>>>(FP, FM, B, ws);
        fdc_kernel<<<256, 256, 0, stream>>>(FP, FM, ws);
    }
    finalize_kernel<<<1, 64, 0, stream>>>(ws, out);
}